// Round 2
// baseline (2332.994 us; speedup 1.0000x reference)
//
#include <hip/hip_runtime.h>
#include <math.h>

#define DIM 64
#define NT 4
#define NR 8

// ---------------- init: m = -inf, den = 0, agg = 0 ----------------
__global__ void init_kernel(float* __restrict__ m, float* __restrict__ den,
                            float* __restrict__ agg, int N) {
    int i = blockIdx.x * blockDim.x + threadIdx.x;
    if (i < N * DIM) agg[i] = 0.f;
    if (i < N) { m[i] = -INFINITY; den[i] = 0.f; }
}

// ------------- fused per-node-type K/Q/V projections -------------
__global__ void proj_kqv(const float* __restrict__ h, const int* __restrict__ ntype,
                         const float* __restrict__ Wk, const float* __restrict__ Wq,
                         const float* __restrict__ Wv,
                         float* __restrict__ k, float* __restrict__ q,
                         float* __restrict__ v, int N) {
    __shared__ float hs[4][DIM];
    int ln = threadIdx.x >> 6;
    int o  = threadIdx.x & 63;
    int n  = blockIdx.x * 4 + ln;
    float hv = 0.f;
    if (n < N) hv = h[(size_t)n * DIM + o];
    hs[ln][o] = hv;
    __syncthreads();
    if (n >= N) return;
    int t = ntype[n];
    const float* wk = Wk + (size_t)t * DIM * DIM;
    const float* wq = Wq + (size_t)t * DIM * DIM;
    const float* wv = Wv + (size_t)t * DIM * DIM;
    float ak = 0.f, aq = 0.f, av = 0.f;
    #pragma unroll 16
    for (int d = 0; d < DIM; d++) {
        float x = hs[ln][d];
        ak = fmaf(x, wk[d * DIM + o], ak);
        aq = fmaf(x, wq[d * DIM + o], aq);
        av = fmaf(x, wv[d * DIM + o], av);
    }
    k[(size_t)n * DIM + o] = ak;
    q[(size_t)n * DIM + o] = aq;
    v[(size_t)n * DIM + o] = av;
}

// --------- out[ry][n][o] = sum_d x[n][d] * Wr[r0+ry][d][o] ---------
__global__ void apply_rel(const float* __restrict__ x, const float* __restrict__ Wr,
                          float* __restrict__ out, int N, int r0) {
    __shared__ float xs[4][DIM];
    int ry = blockIdx.y;
    int ln = threadIdx.x >> 6;
    int o  = threadIdx.x & 63;
    int n  = blockIdx.x * 4 + ln;
    float xv = 0.f;
    if (n < N) xv = x[(size_t)n * DIM + o];
    xs[ln][o] = xv;
    __syncthreads();
    if (n >= N) return;
    const float* w = Wr + (size_t)(r0 + ry) * DIM * DIM;
    float acc = 0.f;
    #pragma unroll 16
    for (int d = 0; d < DIM; d++)
        acc = fmaf(xs[ln][d], w[d * DIM + o], acc);
    out[((size_t)ry * N + n) * DIM + o] = acc;
}

// ---------------- float atomic max (sign-split trick) ----------------
__device__ __forceinline__ void atomicMaxF(float* addr, float val) {
    if (val >= 0.f) atomicMax((int*)addr, __float_as_int(val));
    else            atomicMin((unsigned int*)addr, __float_as_uint(val));
}

// ------- score (chunked): wave per edge; logits[e] + atomicMax into m[dst] -------
__global__ void score_chunk(const float* __restrict__ qW, const float* __restrict__ k,
                            const int* __restrict__ src, const int* __restrict__ dst,
                            const int* __restrict__ et, const float* __restrict__ rel_pri,
                            float* __restrict__ logits, float* __restrict__ m,
                            int N, int E, int r0, int r1) {
    int e = (blockIdx.x * blockDim.x + threadIdx.x) >> 6;
    int l = threadIdx.x & 63;
    if (e >= E) return;
    int r = et[e];
    if (r < r0 || r >= r1) return;
    int s = src[e], d = dst[e];
    float p = qW[((size_t)(r - r0) * N + d) * DIM + l] * k[(size_t)s * DIM + l];
    #pragma unroll
    for (int off = 32; off > 0; off >>= 1) p += __shfl_xor(p, off, 64);
    if (l == 0) {
        float logit = p * rel_pri[r] * 0.125f;  // / sqrt(64)
        logits[e] = logit;
        atomicMaxF(&m[d], logit);
    }
}

// ------- direct (fallback, no qW buffer): score via per-edge bilinear -------
__global__ void score_direct(const float* __restrict__ q, const float* __restrict__ k,
                             const int* __restrict__ src, const int* __restrict__ dst,
                             const int* __restrict__ et, const float* __restrict__ A,
                             const float* __restrict__ rel_pri,
                             float* __restrict__ logits, float* __restrict__ m, int E) {
    int e = (blockIdx.x * blockDim.x + threadIdx.x) >> 6;
    int l = threadIdx.x & 63;
    if (e >= E) return;
    int s = src[e], d = dst[e], r = et[e];
    float qv = q[(size_t)d * DIM + l];
    const float* a = A + (size_t)r * DIM * DIM;
    float t = 0.f;
    #pragma unroll 16
    for (int dd = 0; dd < DIM; dd++)
        t = fmaf(__shfl(qv, dd, 64), a[dd * DIM + l], t);
    float p = t * k[(size_t)s * DIM + l];
    #pragma unroll
    for (int off = 32; off > 0; off >>= 1) p += __shfl_xor(p, off, 64);
    if (l == 0) {
        float logit = p * rel_pri[r] * 0.125f;
        logits[e] = logit;
        atomicMaxF(&m[d], logit);
    }
}

// ---------------- denominator: den[dst] += exp(logit - m) ----------------
__global__ void den_kernel(const float* __restrict__ logits, const int* __restrict__ dst,
                           const float* __restrict__ m, float* __restrict__ den, int E) {
    int e = blockIdx.x * blockDim.x + threadIdx.x;
    if (e >= E) return;
    int d = dst[e];
    atomicAdd(&den[d], expf(logits[e] - m[d]));
}

// ------- aggregate (chunked): agg[dst] += alpha * vW[et-r0, src] -------
__global__ void agg_chunk(const float* __restrict__ vW, const float* __restrict__ logits,
                          const int* __restrict__ src, const int* __restrict__ dst,
                          const int* __restrict__ et,
                          const float* __restrict__ m, const float* __restrict__ den,
                          float* __restrict__ agg, int N, int E, int r0, int r1) {
    int e = (blockIdx.x * blockDim.x + threadIdx.x) >> 6;
    int l = threadIdx.x & 63;
    if (e >= E) return;
    int r = et[e];
    if (r < r0 || r >= r1) return;
    int s = src[e], d = dst[e];
    float dn = den[d];
    float alpha = expf(logits[e] - m[d]) / (dn == 0.f ? 1.f : dn);
    float msg = vW[((size_t)(r - r0) * N + s) * DIM + l];
    atomicAdd(&agg[(size_t)d * DIM + l], alpha * msg);
}

// ------- direct (fallback): aggregate via per-edge bilinear -------
__global__ void agg_direct(const float* __restrict__ v, const float* __restrict__ logits,
                           const int* __restrict__ src, const int* __restrict__ dst,
                           const int* __restrict__ et, const float* __restrict__ Mw,
                           const float* __restrict__ m, const float* __restrict__ den,
                           float* __restrict__ agg, int E) {
    int e = (blockIdx.x * blockDim.x + threadIdx.x) >> 6;
    int l = threadIdx.x & 63;
    if (e >= E) return;
    int s = src[e], d = dst[e], r = et[e];
    float vv = v[(size_t)s * DIM + l];
    const float* w = Mw + (size_t)r * DIM * DIM;
    float t = 0.f;
    #pragma unroll 16
    for (int dd = 0; dd < DIM; dd++)
        t = fmaf(__shfl(vv, dd, 64), w[dd * DIM + l], t);
    float dn = den[d];
    float alpha = expf(logits[e] - m[d]) / (dn == 0.f ? 1.f : dn);
    atomicAdd(&agg[(size_t)d * DIM + l], alpha * t);
}

// ------- output: per-node-type GEMM with sigmoid(skip) scaling -------
__global__ void out_kernel(const float* __restrict__ agg, const int* __restrict__ ntype,
                           const float* __restrict__ Wa, const float* __restrict__ skip,
                           float* __restrict__ out, int N) {
    __shared__ float xs[4][DIM];
    int ln = threadIdx.x >> 6;
    int o  = threadIdx.x & 63;
    int n  = blockIdx.x * 4 + ln;
    float xv = 0.f;
    if (n < N) xv = agg[(size_t)n * DIM + o];
    xs[ln][o] = xv;
    __syncthreads();
    if (n >= N) return;
    int t = ntype[n];
    float sg = 1.f / (1.f + expf(-skip[t]));
    const float* w = Wa + (size_t)t * DIM * DIM;
    float acc = 0.f;
    #pragma unroll 16
    for (int d = 0; d < DIM; d++)
        acc = fmaf(xs[ln][d], w[d * DIM + o], acc);
    out[(size_t)n * DIM + o] = acc * sg;
}

extern "C" void kernel_launch(void* const* d_in, const int* in_sizes, int n_in,
                              void* d_out, int out_size, void* d_ws, size_t ws_size,
                              hipStream_t stream) {
    const float* h       = (const float*)d_in[0];
    const int*   ntype   = (const int*)  d_in[1];
    const int*   src     = (const int*)  d_in[2];
    const int*   dst     = (const int*)  d_in[3];
    const int*   et      = (const int*)  d_in[4];
    const float* k_lin   = (const float*)d_in[5];
    const float* q_lin   = (const float*)d_in[6];
    const float* v_lin   = (const float*)d_in[7];
    const float* a_lin   = (const float*)d_in[8];
    const float* rel_att = (const float*)d_in[9];
    const float* rel_msg = (const float*)d_in[10];
    const float* rel_pri = (const float*)d_in[11];
    const float* skip    = (const float*)d_in[12];

    int N = in_sizes[1];   // node_type
    int E = in_sizes[2];   // src

    float* ws = (float*)d_ws;
    size_t off = 0;
    float* k      = ws + off; off += (size_t)N * DIM;
    float* q      = ws + off; off += (size_t)N * DIM;
    float* v      = ws + off; off += (size_t)N * DIM;
    float* logits = ws + off; off += (size_t)E;
    float* m      = ws + off; off += (size_t)N;
    float* den    = ws + off; off += (size_t)N;
    float* agg    = ws + off; off += (size_t)N * DIM;
    size_t fixed  = off;

    size_t ws_floats = ws_size / sizeof(float);
    size_t avail = (ws_floats > fixed) ? (ws_floats - fixed) : 0;
    int C = (int)(avail / ((size_t)N * DIM));
    if (C > NR) C = NR;
    float* rbuf = ws + fixed;   // C relations of [N x DIM]

    float* out = (float*)d_out;

    init_kernel<<<(N * DIM + 255) / 256, 256, 0, stream>>>(m, den, agg, N);
    proj_kqv<<<(N + 3) / 4, 256, 0, stream>>>(h, ntype, k_lin, q_lin, v_lin, k, q, v, N);

    int eb = (E + 3) / 4;  // wave-per-edge blocks

    if (C >= 1) {
        // --- chunked-precompute path ---
        for (int r0 = 0; r0 < NR; r0 += C) {
            int r1 = r0 + C < NR ? r0 + C : NR;
            apply_rel<<<dim3((N + 3) / 4, r1 - r0), 256, 0, stream>>>(q, rel_att, rbuf, N, r0);
            score_chunk<<<eb, 256, 0, stream>>>(rbuf, k, src, dst, et, rel_pri,
                                                logits, m, N, E, r0, r1);
        }
        den_kernel<<<(E + 255) / 256, 256, 0, stream>>>(logits, dst, m, den, E);
        for (int r0 = 0; r0 < NR; r0 += C) {
            int r1 = r0 + C < NR ? r0 + C : NR;
            apply_rel<<<dim3((N + 3) / 4, r1 - r0), 256, 0, stream>>>(v, rel_msg, rbuf, N, r0);
            agg_chunk<<<eb, 256, 0, stream>>>(rbuf, logits, src, dst, et,
                                              m, den, agg, N, E, r0, r1);
        }
    } else {
        // --- workspace-free fallback: per-edge bilinear ---
        score_direct<<<eb, 256, 0, stream>>>(q, k, src, dst, et, rel_att, rel_pri,
                                             logits, m, E);
        den_kernel<<<(E + 255) / 256, 256, 0, stream>>>(logits, dst, m, den, E);
        agg_direct<<<eb, 256, 0, stream>>>(v, logits, src, dst, et, rel_msg,
                                           m, den, agg, E);
    }

    out_kernel<<<(N + 3) / 4, 256, 0, stream>>>(agg, ntype, a_lin, skip, out, N);
}